// Round 13
// baseline (150.085 us; speedup 1.0000x reference)
//
#include <hip/hip_runtime.h>
#include <hip/hip_bf16.h>
#include <stdint.h>

// Problem constants
#define B_    64
#define T_    200
#define CIN_  80
#define C_    1024
#define M_    (B_ * T_)   // 12800
#define BCEL  (B_ * C_)   // 65536

typedef __attribute__((ext_vector_type(4)))  float f32x4;
typedef __attribute__((ext_vector_type(16))) float f32x16;
typedef __attribute__((ext_vector_type(8)))  _Float16 f16x8;
typedef __attribute__((ext_vector_type(4)))  unsigned int u32x4;

// ---------------------------------------------------------------------------
// Pointwise f32 GEMM (128x128, 8x8/thread, strict ascending-k chains —
// bit-identical arithmetic to r9/r10) MERGED with the vectorized linear
// weight split (blocks 800..1823): saves a launch gap, hides split traffic.
// ---------------------------------------------------------------------------
__global__ __launch_bounds__(256) void pw_and_split(
    const float* __restrict__ A, const float* __restrict__ Bm,
    const float* __restrict__ bias, float* __restrict__ C,
    const float* __restrict__ lw, ushort* __restrict__ w0,
    ushort* __restrict__ w1, int M, int N, int K) {
  __shared__ float As[16][128];
  __shared__ float Bs[16][128];
  const int bx = blockIdx.x;
  const int tid = threadIdx.x;

  if (bx >= 800) {
    // ---- weight split, 4 elems/thread: w ~= w0 + 2^-11 w1s ----
    int base = ((bx - 800) * 256 + tid) * 4;
    float4 xv = *(const float4*)(lw + base);
    float xs[4] = {xv.x, xv.y, xv.z, xv.w};
    ushort o0[4], o1[4];
#pragma unroll
    for (int j = 0; j < 4; ++j) {
      float x = xs[j];
      union { _Float16 h; ushort u; } h0, h1;
      h0.h = (_Float16)x;
      if (fabsf(x) < 6.1035156e-5f) h0.u = 0;   // avoid f16-subnormal w0
      float r = x - (float)h0.h;
      h1.h = (_Float16)(r * 2048.0f);
      o0[j] = h0.u; o1[j] = h1.u;
    }
    *(ushort4*)(w0 + base) = make_ushort4(o0[0], o0[1], o0[2], o0[3]);
    *(ushort4*)(w1 + base) = make_ushort4(o1[0], o1[1], o1[2], o1[3]);
    return;
  }

  const int tx = tid & 15;
  const int ty = tid >> 4;
  const int m0 = (bx % 100) * 128;
  const int n0 = (bx / 100) * 128;
  const int lr = tid >> 1;
  const int lc = (tid & 1) * 8;

  float acc[8][8] = {};
  const float* Ar = A + (size_t)(m0 + lr) * K + lc;
  const float* Br = Bm + (size_t)(n0 + lr) * K + lc;

  float4 a0 = *(const float4*)(Ar + 0);
  float4 a1 = *(const float4*)(Ar + 4);
  float4 b0 = *(const float4*)(Br + 0);
  float4 b1 = *(const float4*)(Br + 4);

  for (int k0 = 0; k0 < K; k0 += 16) {
    __syncthreads();
    As[lc + 0][lr] = a0.x; As[lc + 1][lr] = a0.y;
    As[lc + 2][lr] = a0.z; As[lc + 3][lr] = a0.w;
    As[lc + 4][lr] = a1.x; As[lc + 5][lr] = a1.y;
    As[lc + 6][lr] = a1.z; As[lc + 7][lr] = a1.w;
    Bs[lc + 0][lr] = b0.x; Bs[lc + 1][lr] = b0.y;
    Bs[lc + 2][lr] = b0.z; Bs[lc + 3][lr] = b0.w;
    Bs[lc + 4][lr] = b1.x; Bs[lc + 5][lr] = b1.y;
    Bs[lc + 6][lr] = b1.z; Bs[lc + 7][lr] = b1.w;
    __syncthreads();
    if (k0 + 16 < K) {
      a0 = *(const float4*)(Ar + k0 + 16);
      a1 = *(const float4*)(Ar + k0 + 20);
      b0 = *(const float4*)(Br + k0 + 16);
      b1 = *(const float4*)(Br + k0 + 20);
    }
#pragma unroll
    for (int kk = 0; kk < 16; ++kk) {
      float4 av0 = *(const float4*)&As[kk][ty * 4];
      float4 av1 = *(const float4*)&As[kk][ty * 4 + 64];
      float4 bv0 = *(const float4*)&Bs[kk][tx * 4];
      float4 bv1 = *(const float4*)&Bs[kk][tx * 4 + 64];
      float avv[8] = {av0.x, av0.y, av0.z, av0.w, av1.x, av1.y, av1.z, av1.w};
      float bvv[8] = {bv0.x, bv0.y, bv0.z, bv0.w, bv1.x, bv1.y, bv1.z, bv1.w};
#pragma unroll
      for (int i = 0; i < 8; ++i)
#pragma unroll
        for (int j = 0; j < 8; ++j)
          acc[i][j] = fmaf(avv[i], bvv[j], acc[i][j]);
    }
  }

  float bj[8] = {0.f, 0.f, 0.f, 0.f, 0.f, 0.f, 0.f, 0.f};
#pragma unroll
  for (int j = 0; j < 8; ++j)
    bj[j] = bias[n0 + tx * 4 + (j & 3) + (j >> 2) * 64];
#pragma unroll
  for (int i = 0; i < 8; ++i) {
    int row = m0 + ty * 4 + (i & 3) + (i >> 2) * 64;
    float4 o0, o1;
    o0.x = acc[i][0] + bj[0]; o0.y = acc[i][1] + bj[1];
    o0.z = acc[i][2] + bj[2]; o0.w = acc[i][3] + bj[3];
    o1.x = acc[i][4] + bj[4]; o1.y = acc[i][5] + bj[5];
    o1.z = acc[i][6] + bj[6]; o1.w = acc[i][7] + bj[7];
    *(float4*)&C[(size_t)row * N + n0 + tx * 4] = o0;
    *(float4*)&C[(size_t)row * N + n0 + tx * 4 + 64] = o1;
  }
}

// ---------------------------------------------------------------------------
// Depthwise conv (K=7) + BN1 + LIF1 scan, 8-deep prefetch. [VERBATIM r6]
// ---------------------------------------------------------------------------
__global__ __launch_bounds__(256) void dw_bn_lif(
    const float* __restrict__ p, const float* __restrict__ dw_w,
    const float* __restrict__ dw_b, const float* __restrict__ gam,
    const float* __restrict__ bet, const float* __restrict__ mu,
    const float* __restrict__ var, ushort* __restrict__ s1) {
  int gid = blockIdx.x * blockDim.x + threadIdx.x;
  int b = gid >> 10;
  int o = gid & 1023;

  float w[7];
#pragma unroll
  for (int k = 0; k < 7; ++k) w[k] = dw_w[o * 7 + k];
  float db = dw_b[o];
  float inv = (float)((double)gam[o] / sqrt((double)var[o] + 1e-5));
  float add = (float)((double)bet[o] - (double)mu[o] * (double)inv);

  const float* pp = p + (size_t)b * T_ * C_ + o;
  float win[14];
  win[0] = 0.f; win[1] = 0.f; win[2] = 0.f;
#pragma unroll
  for (int i = 0; i < 11; ++i) win[3 + i] = pp[(size_t)i * C_];

  float v = 0.f;
  size_t obase = (size_t)b * C_ + o;
  for (int c = 0; c < T_ / 8; ++c) {
    int t0 = c * 8;
    float nx[8];
#pragma unroll
    for (int j = 0; j < 8; ++j) {
      int tn = t0 + 11 + j;
      nx[j] = (tn < T_) ? pp[(size_t)tn * C_] : 0.f;
    }
#pragma unroll
    for (int s = 0; s < 8; ++s) {
      float u = db;
#pragma unroll
      for (int k = 0; k < 7; ++k) u = fmaf(w[k], win[s + k], u);
      u = fmaf(u, inv, add);
      v = fmaf(0.5f, v, u);
      bool sp = (v - 1.0f) >= 0.0f;
      s1[obase + (size_t)(t0 + s) * BCEL] = sp ? (ushort)0x3C00 : (ushort)0;
      v = sp ? 0.0f : v;
    }
#pragma unroll
    for (int i = 0; i < 6; ++i) win[i] = win[i + 8];
#pragma unroll
    for (int j = 0; j < 8; ++j) win[6 + j] = nx[j];
  }
}

// ---------------------------------------------------------------------------
// MFMA f16 GEMM, 2-term weight split — 8-phase 256x256 schedule, now with
// 32x32x16 MFMA (half the instructions, 2382-TF ceiling):
//   y = S*w0^T + (S&0x1000)*w1s^T
// 512 threads (8 waves 2Mx4N; per-wave C 128x64 = 4x2 frags of 32x32).
// K-tile=32, 3 LDS slots (144KB) staged 2 tiles ahead, vmcnt(6) at phases
// 4/8 only, setprio around MFMA, r6 XOR swizzle (lane-only row bits).
// Frag layouts [m74/m101]: A/B row=lane&31, k=(lane>>5)*8;
// C/D col=lane&31, row=(reg&3)+8*(reg>>2)+4*(lane>>5).
// ---------------------------------------------------------------------------
#define GBM 256
#define GBN 256
#define GBK 32
#define NKT (C_ / GBK)   // 32

__global__ __launch_bounds__(512, 2) void gemm_mfma32(
    const ushort* __restrict__ A,
    const ushort* __restrict__ B0,
    const ushort* __restrict__ B1,
    float* __restrict__ Cout) {
  const int K = C_;
  const int N = C_;
  __shared__ ushort lds8[3][3][GBM * GBK];   // 144 KB

  const int tid  = threadIdx.x;
  const int lane = tid & 63;
  const int wid  = tid >> 6;
  const int wm = (wid >> 2) * 128;
  const int wn = (wid & 3) * 64;

  // 200 blocks -> 25 contiguous per XCD (bijective)
  int lin = blockIdx.x;
  int wg  = (lin & 7) * 25 + (lin >> 3);
  const int m0 = (wg >> 2) * GBM;
  const int n0 = (wg & 3) * GBN;

  // staging: linear LDS dest, inverse-swizzled global source column
  const int ar0 = tid >> 2, ar1 = ar0 + 128;
  const int aks = ((tid & 3) * 8) ^ (((tid >> 3) & 3) << 3);

  // read-side: row=lane&31 -> swizzle bits ((lane>>1)&3); k-base (lane>>5)*8
  const int l31 = lane & 31;
  const int rsw = ((lane >> 1) & 3) << 3;
  const int kb8 = (lane >> 5) * 8;

  f32x16 acc[4][2] = {};

#define STG(MATP, RB, MI, SLOT, K0S)                                           \
  do {                                                                         \
    __builtin_amdgcn_global_load_lds(                                          \
        (const __attribute__((address_space(1))) uint32_t*)((MATP) + (size_t)((RB) + ar0) * K + (K0S) + aks), \
        (__attribute__((address_space(3))) uint32_t*)&lds8[SLOT][MI][tid * 8], 16, 0, 0);                     \
    __builtin_amdgcn_global_load_lds(                                          \
        (const __attribute__((address_space(1))) uint32_t*)((MATP) + (size_t)((RB) + ar1) * K + (K0S) + aks), \
        (__attribute__((address_space(3))) uint32_t*)&lds8[SLOT][MI][(tid + 512) * 8], 16, 0, 0);             \
  } while (0)

#define NOSTG ((void)0)
#define VM6 asm volatile("s_waitcnt vmcnt(6)" ::: "memory")

  // Phase Q: m-blocks {(Q&1)*2, +1}, n-block (Q>>1). 8 ds_read_b128,
  // 8 MFMA 32x32x16. Per-fragment k order: kch0 base, kch0 mask, kch1 base,
  // kch1 mask — fixed across all tiles.
#define PHASE(Q, SRD, STAGE_STMT, VMSTMT)                                      \
  do {                                                                         \
    constexpr int MB = ((Q) & 1) * 2;                                          \
    constexpr int NB = ((Q) >> 1);                                             \
    const ushort* As_  = &lds8[SRD][0][0];                                     \
    const ushort* B0s_ = &lds8[SRD][1][0];                                     \
    const ushort* B1s_ = &lds8[SRD][2][0];                                     \
    f16x8 aa[2][2], bb0[2], bb1[2];                                            \
    _Pragma("unroll")                                                          \
    for (int mb = 0; mb < 2; ++mb)                                             \
      _Pragma("unroll")                                                        \
      for (int kc = 0; kc < 2; ++kc)                                           \
        aa[mb][kc] = *(const f16x8*)&As_[(wm + (MB + mb) * 32 + l31) * GBK +   \
                                         ((kc * 16 + kb8) ^ rsw)];             \
    _Pragma("unroll")                                                          \
    for (int kc = 0; kc < 2; ++kc) {                                           \
      bb0[kc] = *(const f16x8*)&B0s_[(wn + NB * 32 + l31) * GBK +              \
                                     ((kc * 16 + kb8) ^ rsw)];                 \
      bb1[kc] = *(const f16x8*)&B1s_[(wn + NB * 32 + l31) * GBK +              \
                                     ((kc * 16 + kb8) ^ rsw)];                 \
    }                                                                          \
    STAGE_STMT;                                                                \
    __builtin_amdgcn_s_barrier();                                              \
    asm volatile("s_waitcnt lgkmcnt(0)" ::: "memory");                         \
    __builtin_amdgcn_s_setprio(1);                                             \
    union HU_ { f16x8 h; u32x4 u; };                                           \
    _Pragma("unroll")                                                          \
    for (int mb = 0; mb < 2; ++mb) {                                           \
      _Pragma("unroll")                                                        \
      for (int kc = 0; kc < 2; ++kc) {                                         \
        HU_ xm_;                                                               \
        xm_.h = aa[mb][kc];                                                    \
        xm_.u &= 0x10001000u;   /* {0,1.0f16} -> {0,2^-11} exactly */          \
        acc[MB + mb][NB] = __builtin_amdgcn_mfma_f32_32x32x16_f16(             \
            aa[mb][kc], bb0[kc], acc[MB + mb][NB], 0, 0, 0);                   \
        acc[MB + mb][NB] = __builtin_amdgcn_mfma_f32_32x32x16_f16(             \
            xm_.h, bb1[kc], acc[MB + mb][NB], 0, 0, 0);                        \
      }                                                                        \
    }                                                                          \
    __builtin_amdgcn_s_setprio(0);                                             \
    VMSTMT;                                                                    \
    __builtin_amdgcn_s_barrier();                                              \
  } while (0)

  // prologue: stage tiles 0,1 -> slots 0,1; wait tile0 (tile1's 6 in flight)
  STG(A, m0, 0, 0, 0);  STG(B0, n0, 1, 0, 0);  STG(B1, n0, 2, 0, 0);
  STG(A, m0, 0, 1, GBK); STG(B0, n0, 1, 1, GBK); STG(B1, n0, 2, 1, GBK);
  asm volatile("s_waitcnt vmcnt(6)" ::: "memory");
  __builtin_amdgcn_s_barrier();

  int s0 = 0;
  for (int it = 0; it < NKT / 2; ++it) {
    const int t0 = 2 * it;
    int s1 = s0 + 1; if (s1 == 3) s1 = 0;
    int s2 = s1 + 1; if (s2 == 3) s2 = 0;
    const int ka = (t0 + 2 < NKT) ? (t0 + 2) * GBK : 0;   // clamped dummy
    const int kb = (t0 + 3 < NKT) ? (t0 + 3) * GBK : 0;
    PHASE(0, s0, STG(A,  m0, 0, s2, ka), NOSTG);
    PHASE(1, s0, STG(B0, n0, 1, s2, ka), NOSTG);
    PHASE(2, s0, STG(B1, n0, 2, s2, ka), NOSTG);
    PHASE(3, s0, NOSTG, VM6);
    PHASE(0, s1, STG(A,  m0, 0, s0, kb), NOSTG);
    PHASE(1, s1, STG(B0, n0, 1, s0, kb), NOSTG);
    PHASE(2, s1, STG(B1, n0, 2, s0, kb), NOSTG);
    PHASE(3, s1, NOSTG, VM6);
    s0 = s2;
  }
#undef PHASE
#undef STG

  // epilogue: 32x32 C/D layout: col=lane&31, row=(reg&3)+8*(reg>>2)+4*(l>>5)
  const int rbase = (lane >> 5) * 4;
#pragma unroll
  for (int mb = 0; mb < 4; ++mb)
#pragma unroll
    for (int nb = 0; nb < 2; ++nb)
#pragma unroll
      for (int rg = 0; rg < 16; ++rg) {
        int row = m0 + wm + mb * 32 + (rg & 3) + 8 * (rg >> 2) + rbase;
        int col = n0 + wn + nb * 32 + l31;
        Cout[(size_t)row * N + col] = acc[mb][nb][rg];
      }
}

// ---------------------------------------------------------------------------
// BN2 + LIF2 + residual, 8-deep prefetch. [VERBATIM r6]
// ---------------------------------------------------------------------------
__global__ __launch_bounds__(256) void bn_lif_add(
    const float* __restrict__ y, const ushort* __restrict__ s1b,
    const float* __restrict__ gam, const float* __restrict__ bet,
    const float* __restrict__ mu, const float* __restrict__ var,
    float* __restrict__ out) {
  int gid = blockIdx.x * blockDim.x + threadIdx.x;
  int o = gid & 1023;

  float inv = (float)((double)gam[o] / sqrt((double)var[o] + 1e-5));
  float add = (float)((double)bet[o] - (double)mu[o] * (double)inv);

  float v = 0.f;
  size_t base = (size_t)gid;
  float yv[8]; ushort sv[8];
#pragma unroll
  for (int j = 0; j < 8; ++j) {
    yv[j] = y[base + (size_t)j * BCEL];
    sv[j] = s1b[base + (size_t)j * BCEL];
  }
  for (int c = 0; c < T_ / 8; ++c) {
    int t0 = c * 8;
    float yn[8] = {0,0,0,0,0,0,0,0}; ushort sn[8] = {0,0,0,0,0,0,0,0};
    if (c + 1 < T_ / 8) {
#pragma unroll
      for (int j = 0; j < 8; ++j) {
        size_t idx = base + (size_t)(t0 + 8 + j) * BCEL;
        yn[j] = y[idx];
        sn[j] = s1b[idx];
      }
    }
#pragma unroll
    for (int j = 0; j < 8; ++j) {
      float u = fmaf(yv[j], inv, add);
      v = fmaf(0.5f, v, u);
      bool sp = (v - 1.0f) >= 0.0f;
      float s1v = sv[j] ? 1.0f : 0.0f;
      out[base + (size_t)(t0 + j) * BCEL] = (sp ? 1.0f : 0.0f) + s1v;
      v = sp ? 0.0f : v;
    }
#pragma unroll
    for (int j = 0; j < 8; ++j) { yv[j] = yn[j]; sv[j] = sn[j]; }
  }
}

// ---------------------------------------------------------------------------
extern "C" void kernel_launch(void* const* d_in, const int* in_sizes, int n_in,
                              void* d_out, int out_size, void* d_ws,
                              size_t ws_size, hipStream_t stream) {
  const float* x     = (const float*)d_in[0];
  const float* pw_w  = (const float*)d_in[1];
  const float* pw_b  = (const float*)d_in[2];
  const float* dw_w  = (const float*)d_in[3];
  const float* dw_b  = (const float*)d_in[4];
  const float* bn1g  = (const float*)d_in[5];
  const float* bn1b  = (const float*)d_in[6];
  const float* bn1m  = (const float*)d_in[7];
  const float* bn1v  = (const float*)d_in[8];
  const float* lin_w = (const float*)d_in[9];
  const float* bn2g  = (const float*)d_in[10];
  const float* bn2b  = (const float*)d_in[11];
  const float* bn2m  = (const float*)d_in[12];
  const float* bn2v  = (const float*)d_in[13];

  char* wsb  = (char*)d_ws;
  char* outb = (char*)d_out;
  const size_t PB  = (size_t)M_ * C_ * 4;        // 52,428,800  (p / y, f32)
  const size_t SBB = (size_t)M_ * C_ * 2;        // 26,214,400  (spikes, f16)

  float* p = (float*)d_ws;                       // [B,T,C] f32

  const bool primary = ws_size >= PB + SBB;
  // primary : spikes @ ws+PB, lin-weights @ d_out[0:4MB), y @ ws[0:PB)
  // fallback: spikes @ d_out, memcpy -> ws[0:SBB), weights @ ws+SBB, y @ d_out
  ushort* spikes = primary ? (ushort*)(wsb + PB) : (ushort*)d_out;
  ushort* w0  = primary ? (ushort*)outb : (ushort*)(wsb + SBB);
  ushort* w1s = w0 + (size_t)C_ * C_;
  ushort* Sgemm = primary ? spikes : (ushort*)d_ws;
  float* ybuf = primary ? (float*)d_ws : (float*)d_out;

  // 1) pointwise conv (f32 GEMM, exact) + linear weight split, one dispatch
  pw_and_split<<<800 + 1024, 256, 0, stream>>>(x, pw_w, pw_b, p, lin_w, w0,
                                               w1s, M_, C_, CIN_);

  // 2) depthwise + BN1 + LIF1 -> f16 spike bits [T,B,C]
  dw_bn_lif<<<BCEL / 256, 256, 0, stream>>>(p, dw_w, dw_b, bn1g, bn1b, bn1m,
                                            bn1v, spikes);

  // 3) fallback only: move spikes out of d_out before GEMM overwrites it
  if (!primary)
    hipMemcpyAsync(d_ws, d_out, SBB, hipMemcpyDeviceToDevice, stream);

  // 4) linear MFMA GEMM (8-phase 256^2, 32x32x16): y = S.(w0 + 2^-11 w1s)^T
  gemm_mfma32<<<(M_ / GBM) * (C_ / GBN), 512, 0, stream>>>(Sgemm, w0, w1s,
                                                           ybuf);

  // 5) BN2 + LIF2 + residual -> d_out
  bn_lif_add<<<BCEL / 256, 256, 0, stream>>>(ybuf, Sgemm, bn2g, bn2b, bn2m,
                                             bn2v, (float*)d_out);
}

// Round 15
// 144.127 us; speedup vs baseline: 1.0413x; 1.0413x over previous
//
#include <hip/hip_runtime.h>
#include <hip/hip_bf16.h>
#include <stdint.h>

// Problem constants
#define B_    64
#define T_    200
#define CIN_  80
#define C_    1024
#define M_    (B_ * T_)   // 12800
#define BCEL  (B_ * C_)   // 65536

typedef __attribute__((ext_vector_type(4)))  float f32x4;
typedef __attribute__((ext_vector_type(8)))  _Float16 f16x8;
typedef __attribute__((ext_vector_type(4)))  unsigned int u32x4;

// ---------------------------------------------------------------------------
// Pointwise f32 GEMM (128x128, 8x8/thread, strict ascending-k chains —
// bit-identical arithmetic to r9..r13) MERGED with the vectorized linear
// weight split (blocks 800..1823). [VERBATIM r13 — the merge saved ~5us]
// ---------------------------------------------------------------------------
__global__ __launch_bounds__(256) void pw_and_split(
    const float* __restrict__ A, const float* __restrict__ Bm,
    const float* __restrict__ bias, float* __restrict__ C,
    const float* __restrict__ lw, ushort* __restrict__ w0,
    ushort* __restrict__ w1, int M, int N, int K) {
  __shared__ float As[16][128];
  __shared__ float Bs[16][128];
  const int bx = blockIdx.x;
  const int tid = threadIdx.x;

  if (bx >= 800) {
    int base = ((bx - 800) * 256 + tid) * 4;
    float4 xv = *(const float4*)(lw + base);
    float xs[4] = {xv.x, xv.y, xv.z, xv.w};
    ushort o0[4], o1[4];
#pragma unroll
    for (int j = 0; j < 4; ++j) {
      float x = xs[j];
      union { _Float16 h; ushort u; } h0, h1;
      h0.h = (_Float16)x;
      if (fabsf(x) < 6.1035156e-5f) h0.u = 0;   // avoid f16-subnormal w0
      float r = x - (float)h0.h;
      h1.h = (_Float16)(r * 2048.0f);
      o0[j] = h0.u; o1[j] = h1.u;
    }
    *(ushort4*)(w0 + base) = make_ushort4(o0[0], o0[1], o0[2], o0[3]);
    *(ushort4*)(w1 + base) = make_ushort4(o1[0], o1[1], o1[2], o1[3]);
    return;
  }

  const int tx = tid & 15;
  const int ty = tid >> 4;
  const int m0 = (bx % 100) * 128;
  const int n0 = (bx / 100) * 128;
  const int lr = tid >> 1;
  const int lc = (tid & 1) * 8;

  float acc[8][8] = {};
  const float* Ar = A + (size_t)(m0 + lr) * K + lc;
  const float* Br = Bm + (size_t)(n0 + lr) * K + lc;

  float4 a0 = *(const float4*)(Ar + 0);
  float4 a1 = *(const float4*)(Ar + 4);
  float4 b0 = *(const float4*)(Br + 0);
  float4 b1 = *(const float4*)(Br + 4);

  for (int k0 = 0; k0 < K; k0 += 16) {
    __syncthreads();
    As[lc + 0][lr] = a0.x; As[lc + 1][lr] = a0.y;
    As[lc + 2][lr] = a0.z; As[lc + 3][lr] = a0.w;
    As[lc + 4][lr] = a1.x; As[lc + 5][lr] = a1.y;
    As[lc + 6][lr] = a1.z; As[lc + 7][lr] = a1.w;
    Bs[lc + 0][lr] = b0.x; Bs[lc + 1][lr] = b0.y;
    Bs[lc + 2][lr] = b0.z; Bs[lc + 3][lr] = b0.w;
    Bs[lc + 4][lr] = b1.x; Bs[lc + 5][lr] = b1.y;
    Bs[lc + 6][lr] = b1.z; Bs[lc + 7][lr] = b1.w;
    __syncthreads();
    if (k0 + 16 < K) {
      a0 = *(const float4*)(Ar + k0 + 16);
      a1 = *(const float4*)(Ar + k0 + 20);
      b0 = *(const float4*)(Br + k0 + 16);
      b1 = *(const float4*)(Br + k0 + 20);
    }
#pragma unroll
    for (int kk = 0; kk < 16; ++kk) {
      float4 av0 = *(const float4*)&As[kk][ty * 4];
      float4 av1 = *(const float4*)&As[kk][ty * 4 + 64];
      float4 bv0 = *(const float4*)&Bs[kk][tx * 4];
      float4 bv1 = *(const float4*)&Bs[kk][tx * 4 + 64];
      float avv[8] = {av0.x, av0.y, av0.z, av0.w, av1.x, av1.y, av1.z, av1.w};
      float bvv[8] = {bv0.x, bv0.y, bv0.z, bv0.w, bv1.x, bv1.y, bv1.z, bv1.w};
#pragma unroll
      for (int i = 0; i < 8; ++i)
#pragma unroll
        for (int j = 0; j < 8; ++j)
          acc[i][j] = fmaf(avv[i], bvv[j], acc[i][j]);
    }
  }

  float bj[8] = {0.f, 0.f, 0.f, 0.f, 0.f, 0.f, 0.f, 0.f};
#pragma unroll
  for (int j = 0; j < 8; ++j)
    bj[j] = bias[n0 + tx * 4 + (j & 3) + (j >> 2) * 64];
#pragma unroll
  for (int i = 0; i < 8; ++i) {
    int row = m0 + ty * 4 + (i & 3) + (i >> 2) * 64;
    float4 o0, o1;
    o0.x = acc[i][0] + bj[0]; o0.y = acc[i][1] + bj[1];
    o0.z = acc[i][2] + bj[2]; o0.w = acc[i][3] + bj[3];
    o1.x = acc[i][4] + bj[4]; o1.y = acc[i][5] + bj[5];
    o1.z = acc[i][6] + bj[6]; o1.w = acc[i][7] + bj[7];
    *(float4*)&C[(size_t)row * N + n0 + tx * 4] = o0;
    *(float4*)&C[(size_t)row * N + n0 + tx * 4 + 64] = o1;
  }
}

// ---------------------------------------------------------------------------
// Depthwise conv (K=7) + BN1 + LIF1 scan, 8-deep prefetch. [VERBATIM r6]
// ---------------------------------------------------------------------------
__global__ __launch_bounds__(256) void dw_bn_lif(
    const float* __restrict__ p, const float* __restrict__ dw_w,
    const float* __restrict__ dw_b, const float* __restrict__ gam,
    const float* __restrict__ bet, const float* __restrict__ mu,
    const float* __restrict__ var, ushort* __restrict__ s1) {
  int gid = blockIdx.x * blockDim.x + threadIdx.x;
  int b = gid >> 10;
  int o = gid & 1023;

  float w[7];
#pragma unroll
  for (int k = 0; k < 7; ++k) w[k] = dw_w[o * 7 + k];
  float db = dw_b[o];
  float inv = (float)((double)gam[o] / sqrt((double)var[o] + 1e-5));
  float add = (float)((double)bet[o] - (double)mu[o] * (double)inv);

  const float* pp = p + (size_t)b * T_ * C_ + o;
  float win[14];
  win[0] = 0.f; win[1] = 0.f; win[2] = 0.f;
#pragma unroll
  for (int i = 0; i < 11; ++i) win[3 + i] = pp[(size_t)i * C_];

  float v = 0.f;
  size_t obase = (size_t)b * C_ + o;
  for (int c = 0; c < T_ / 8; ++c) {
    int t0 = c * 8;
    float nx[8];
#pragma unroll
    for (int j = 0; j < 8; ++j) {
      int tn = t0 + 11 + j;
      nx[j] = (tn < T_) ? pp[(size_t)tn * C_] : 0.f;
    }
#pragma unroll
    for (int s = 0; s < 8; ++s) {
      float u = db;
#pragma unroll
      for (int k = 0; k < 7; ++k) u = fmaf(w[k], win[s + k], u);
      u = fmaf(u, inv, add);
      v = fmaf(0.5f, v, u);
      bool sp = (v - 1.0f) >= 0.0f;
      s1[obase + (size_t)(t0 + s) * BCEL] = sp ? (ushort)0x3C00 : (ushort)0;
      v = sp ? 0.0f : v;
    }
#pragma unroll
    for (int i = 0; i < 6; ++i) win[i] = win[i + 8];
#pragma unroll
    for (int j = 0; j < 8; ++j) win[6 + j] = nx[j];
  }
}

// ---------------------------------------------------------------------------
// MFMA f16 GEMM, 2-term weight split — 8-PHASE 256x256 schedule, 16x16x32
// MFMA (the r10-proven config: 72.5us, 0 bank conflicts):
//   y = S*w0^T + (S&0x1000)*w1s^T
// 512 threads (8 waves 2Mx4N; per-wave C 128x64). K-tile=32, 3 LDS slots
// (144KB) staged 2 tiles ahead, vmcnt(6) at phases 4/8 only, setprio around
// MFMA, r6 XOR swizzle. [VERBATIM r10 gemm_mfma8p]
// ---------------------------------------------------------------------------
#define GBM 256
#define GBN 256
#define GBK 32
#define NKT (C_ / GBK)   // 32

__global__ __launch_bounds__(512, 2) void gemm_mfma8p(
    const ushort* __restrict__ A,
    const ushort* __restrict__ B0,
    const ushort* __restrict__ B1,
    float* __restrict__ Cout) {
  const int K = C_;
  const int N = C_;
  __shared__ ushort lds8[3][3][GBM * GBK];   // 144 KB

  const int tid  = threadIdx.x;
  const int lane = tid & 63;
  const int wid  = tid >> 6;
  const int wm = (wid >> 2) * 128;   // 2 M-groups of waves
  const int wn = (wid & 3) * 64;     // 4 N-groups

  // 200 blocks -> 25 contiguous per XCD (bijective)
  int lin = blockIdx.x;
  int wg  = (lin & 7) * 25 + (lin >> 3);
  const int m0 = (wg >> 2) * GBM;
  const int n0 = (wg & 3) * GBN;

  // staging geometry; source column pre-inverse-swizzled
  const int ar0 = tid >> 2, ar1 = ar0 + 128;
  const int aks = ((tid & 3) * 8) ^ (((tid >> 3) & 3) << 3);

  // read-side fragment indices (swizzled column)
  const int fr  = lane & 15;
  const int k8s = ((lane >> 4) * 8) ^ (((fr >> 1) & 3) << 3);

  f32x4 acc[8][4] = {};

#define STG(MATP, RB, MI, SLOT, K0S)                                           \
  do {                                                                         \
    __builtin_amdgcn_global_load_lds(                                          \
        (const __attribute__((address_space(1))) uint32_t*)((MATP) + (size_t)((RB) + ar0) * K + (K0S) + aks), \
        (__attribute__((address_space(3))) uint32_t*)&lds8[SLOT][MI][tid * 8], 16, 0, 0);                     \
    __builtin_amdgcn_global_load_lds(                                          \
        (const __attribute__((address_space(1))) uint32_t*)((MATP) + (size_t)((RB) + ar1) * K + (K0S) + aks), \
        (__attribute__((address_space(3))) uint32_t*)&lds8[SLOT][MI][(tid + 512) * 8], 16, 0, 0);             \
  } while (0)

#define NOSTG ((void)0)
#define VM6 asm volatile("s_waitcnt vmcnt(6)" ::: "memory")

#define PHASE(Q, SRD, STAGE_STMT, VMSTMT)                                      \
  do {                                                                         \
    constexpr int FRB = ((Q) & 1) * 4;                                         \
    constexpr int FCB = ((Q) >> 1) * 2;                                        \
    const ushort* As_  = &lds8[SRD][0][0];                                     \
    const ushort* B0s_ = &lds8[SRD][1][0];                                     \
    const ushort* B1s_ = &lds8[SRD][2][0];                                     \
    f16x8 a0_ = *(const f16x8*)&As_[(wm + (FRB + 0) * 16 + fr) * GBK + k8s];   \
    f16x8 a1_ = *(const f16x8*)&As_[(wm + (FRB + 1) * 16 + fr) * GBK + k8s];   \
    f16x8 a2_ = *(const f16x8*)&As_[(wm + (FRB + 2) * 16 + fr) * GBK + k8s];   \
    f16x8 a3_ = *(const f16x8*)&As_[(wm + (FRB + 3) * 16 + fr) * GBK + k8s];   \
    f16x8 p0_ = *(const f16x8*)&B0s_[(wn + (FCB + 0) * 16 + fr) * GBK + k8s];  \
    f16x8 p1_ = *(const f16x8*)&B0s_[(wn + (FCB + 1) * 16 + fr) * GBK + k8s];  \
    f16x8 q0_ = *(const f16x8*)&B1s_[(wn + (FCB + 0) * 16 + fr) * GBK + k8s];  \
    f16x8 q1_ = *(const f16x8*)&B1s_[(wn + (FCB + 1) * 16 + fr) * GBK + k8s];  \
    STAGE_STMT;                                                                \
    __builtin_amdgcn_s_barrier();                                              \
    asm volatile("s_waitcnt lgkmcnt(0)" ::: "memory");                         \
    __builtin_amdgcn_s_setprio(1);                                             \
    union HU_ { f16x8 h; u32x4 u; };                                           \
    HU_ x0_, x1_, x2_, x3_;                                                    \
    x0_.h = a0_; x0_.u &= 0x10001000u;                                         \
    x1_.h = a1_; x1_.u &= 0x10001000u;                                         \
    x2_.h = a2_; x2_.u &= 0x10001000u;                                         \
    x3_.h = a3_; x3_.u &= 0x10001000u;                                         \
    acc[FRB + 0][FCB + 0] = __builtin_amdgcn_mfma_f32_16x16x32_f16(a0_, p0_, acc[FRB + 0][FCB + 0], 0, 0, 0); \
    acc[FRB + 0][FCB + 0] = __builtin_amdgcn_mfma_f32_16x16x32_f16(x0_.h, q0_, acc[FRB + 0][FCB + 0], 0, 0, 0); \
    acc[FRB + 1][FCB + 0] = __builtin_amdgcn_mfma_f32_16x16x32_f16(a1_, p0_, acc[FRB + 1][FCB + 0], 0, 0, 0); \
    acc[FRB + 1][FCB + 0] = __builtin_amdgcn_mfma_f32_16x16x32_f16(x1_.h, q0_, acc[FRB + 1][FCB + 0], 0, 0, 0); \
    acc[FRB + 2][FCB + 0] = __builtin_amdgcn_mfma_f32_16x16x32_f16(a2_, p0_, acc[FRB + 2][FCB + 0], 0, 0, 0); \
    acc[FRB + 2][FCB + 0] = __builtin_amdgcn_mfma_f32_16x16x32_f16(x2_.h, q0_, acc[FRB + 2][FCB + 0], 0, 0, 0); \
    acc[FRB + 3][FCB + 0] = __builtin_amdgcn_mfma_f32_16x16x32_f16(a3_, p0_, acc[FRB + 3][FCB + 0], 0, 0, 0); \
    acc[FRB + 3][FCB + 0] = __builtin_amdgcn_mfma_f32_16x16x32_f16(x3_.h, q0_, acc[FRB + 3][FCB + 0], 0, 0, 0); \
    acc[FRB + 0][FCB + 1] = __builtin_amdgcn_mfma_f32_16x16x32_f16(a0_, p1_, acc[FRB + 0][FCB + 1], 0, 0, 0); \
    acc[FRB + 0][FCB + 1] = __builtin_amdgcn_mfma_f32_16x16x32_f16(x0_.h, q1_, acc[FRB + 0][FCB + 1], 0, 0, 0); \
    acc[FRB + 1][FCB + 1] = __builtin_amdgcn_mfma_f32_16x16x32_f16(a1_, p1_, acc[FRB + 1][FCB + 1], 0, 0, 0); \
    acc[FRB + 1][FCB + 1] = __builtin_amdgcn_mfma_f32_16x16x32_f16(x1_.h, q1_, acc[FRB + 1][FCB + 1], 0, 0, 0); \
    acc[FRB + 2][FCB + 1] = __builtin_amdgcn_mfma_f32_16x16x32_f16(a2_, p1_, acc[FRB + 2][FCB + 1], 0, 0, 0); \
    acc[FRB + 2][FCB + 1] = __builtin_amdgcn_mfma_f32_16x16x32_f16(x2_.h, q1_, acc[FRB + 2][FCB + 1], 0, 0, 0); \
    acc[FRB + 3][FCB + 1] = __builtin_amdgcn_mfma_f32_16x16x32_f16(a3_, p1_, acc[FRB + 3][FCB + 1], 0, 0, 0); \
    acc[FRB + 3][FCB + 1] = __builtin_amdgcn_mfma_f32_16x16x32_f16(x3_.h, q1_, acc[FRB + 3][FCB + 1], 0, 0, 0); \
    __builtin_amdgcn_s_setprio(0);                                             \
    VMSTMT;                                                                    \
    __builtin_amdgcn_s_barrier();                                              \
  } while (0)

  // prologue: stage tiles 0,1 -> slots 0,1; wait tile0 (tile1's 6 in flight)
  STG(A, m0, 0, 0, 0);  STG(B0, n0, 1, 0, 0);  STG(B1, n0, 2, 0, 0);
  STG(A, m0, 0, 1, GBK); STG(B0, n0, 1, 1, GBK); STG(B1, n0, 2, 1, GBK);
  asm volatile("s_waitcnt vmcnt(6)" ::: "memory");
  __builtin_amdgcn_s_barrier();

  int s0 = 0;
  for (int it = 0; it < NKT / 2; ++it) {
    const int t0 = 2 * it;
    int s1 = s0 + 1; if (s1 == 3) s1 = 0;
    int s2 = s1 + 1; if (s2 == 3) s2 = 0;
    const int ka = (t0 + 2 < NKT) ? (t0 + 2) * GBK : 0;   // clamped dummy
    const int kb = (t0 + 3 < NKT) ? (t0 + 3) * GBK : 0;
    PHASE(0, s0, STG(A,  m0, 0, s2, ka), NOSTG);
    PHASE(1, s0, STG(B0, n0, 1, s2, ka), NOSTG);
    PHASE(2, s0, STG(B1, n0, 2, s2, ka), NOSTG);
    PHASE(3, s0, NOSTG, VM6);
    PHASE(0, s1, STG(A,  m0, 0, s0, kb), NOSTG);
    PHASE(1, s1, STG(B0, n0, 1, s0, kb), NOSTG);
    PHASE(2, s1, STG(B1, n0, 2, s0, kb), NOSTG);
    PHASE(3, s1, NOSTG, VM6);
    s0 = s2;
  }
#undef PHASE
#undef STG

  // epilogue: C/D layout col=lane&15, row=(lane>>4)*4+j
  const int ccol = lane & 15;
  const int crow = (lane >> 4) * 4;
#pragma unroll
  for (int m = 0; m < 8; ++m)
#pragma unroll
    for (int n = 0; n < 4; ++n)
#pragma unroll
      for (int j = 0; j < 4; ++j) {
        int row = m0 + wm + m * 16 + crow + j;
        int col = n0 + wn + n * 16 + ccol;
        Cout[(size_t)row * N + col] = acc[m][n][j];
      }
}

// ---------------------------------------------------------------------------
// BN2 + LIF2 + residual, 8-deep prefetch. [VERBATIM r6]
// ---------------------------------------------------------------------------
__global__ __launch_bounds__(256) void bn_lif_add(
    const float* __restrict__ y, const ushort* __restrict__ s1b,
    const float* __restrict__ gam, const float* __restrict__ bet,
    const float* __restrict__ mu, const float* __restrict__ var,
    float* __restrict__ out) {
  int gid = blockIdx.x * blockDim.x + threadIdx.x;
  int o = gid & 1023;

  float inv = (float)((double)gam[o] / sqrt((double)var[o] + 1e-5));
  float add = (float)((double)bet[o] - (double)mu[o] * (double)inv);

  float v = 0.f;
  size_t base = (size_t)gid;
  float yv[8]; ushort sv[8];
#pragma unroll
  for (int j = 0; j < 8; ++j) {
    yv[j] = y[base + (size_t)j * BCEL];
    sv[j] = s1b[base + (size_t)j * BCEL];
  }
  for (int c = 0; c < T_ / 8; ++c) {
    int t0 = c * 8;
    float yn[8] = {0,0,0,0,0,0,0,0}; ushort sn[8] = {0,0,0,0,0,0,0,0};
    if (c + 1 < T_ / 8) {
#pragma unroll
      for (int j = 0; j < 8; ++j) {
        size_t idx = base + (size_t)(t0 + 8 + j) * BCEL;
        yn[j] = y[idx];
        sn[j] = s1b[idx];
      }
    }
#pragma unroll
    for (int j = 0; j < 8; ++j) {
      float u = fmaf(yv[j], inv, add);
      v = fmaf(0.5f, v, u);
      bool sp = (v - 1.0f) >= 0.0f;
      float s1v = sv[j] ? 1.0f : 0.0f;
      out[base + (size_t)(t0 + j) * BCEL] = (sp ? 1.0f : 0.0f) + s1v;
      v = sp ? 0.0f : v;
    }
#pragma unroll
    for (int j = 0; j < 8; ++j) { yv[j] = yn[j]; sv[j] = sn[j]; }
  }
}

// ---------------------------------------------------------------------------
extern "C" void kernel_launch(void* const* d_in, const int* in_sizes, int n_in,
                              void* d_out, int out_size, void* d_ws,
                              size_t ws_size, hipStream_t stream) {
  const float* x     = (const float*)d_in[0];
  const float* pw_w  = (const float*)d_in[1];
  const float* pw_b  = (const float*)d_in[2];
  const float* dw_w  = (const float*)d_in[3];
  const float* dw_b  = (const float*)d_in[4];
  const float* bn1g  = (const float*)d_in[5];
  const float* bn1b  = (const float*)d_in[6];
  const float* bn1m  = (const float*)d_in[7];
  const float* bn1v  = (const float*)d_in[8];
  const float* lin_w = (const float*)d_in[9];
  const float* bn2g  = (const float*)d_in[10];
  const float* bn2b  = (const float*)d_in[11];
  const float* bn2m  = (const float*)d_in[12];
  const float* bn2v  = (const float*)d_in[13];

  char* wsb  = (char*)d_ws;
  char* outb = (char*)d_out;
  const size_t PB  = (size_t)M_ * C_ * 4;        // 52,428,800  (p / y, f32)
  const size_t SBB = (size_t)M_ * C_ * 2;        // 26,214,400  (spikes, f16)

  float* p = (float*)d_ws;                       // [B,T,C] f32

  const bool primary = ws_size >= PB + SBB;
  // primary : spikes @ ws+PB, lin-weights @ d_out[0:4MB), y @ ws[0:PB)
  // fallback: spikes @ d_out, memcpy -> ws[0:SBB), weights @ ws+SBB, y @ d_out
  ushort* spikes = primary ? (ushort*)(wsb + PB) : (ushort*)d_out;
  ushort* w0  = primary ? (ushort*)outb : (ushort*)(wsb + SBB);
  ushort* w1s = w0 + (size_t)C_ * C_;
  ushort* Sgemm = primary ? spikes : (ushort*)d_ws;
  float* ybuf = primary ? (float*)d_ws : (float*)d_out;

  // 1) pointwise conv (f32 GEMM, exact) + linear weight split, one dispatch
  pw_and_split<<<800 + 1024, 256, 0, stream>>>(x, pw_w, pw_b, p, lin_w, w0,
                                               w1s, M_, C_, CIN_);

  // 2) depthwise + BN1 + LIF1 -> f16 spike bits [T,B,C]
  dw_bn_lif<<<BCEL / 256, 256, 0, stream>>>(p, dw_w, dw_b, bn1g, bn1b, bn1m,
                                            bn1v, spikes);

  // 3) fallback only: move spikes out of d_out before GEMM overwrites it
  if (!primary)
    hipMemcpyAsync(d_ws, d_out, SBB, hipMemcpyDeviceToDevice, stream);

  // 4) linear MFMA GEMM (8-phase 256^2, 16x16x32): y = S.(w0 + 2^-11 w1s)^T
  gemm_mfma8p<<<(M_ / GBM) * (C_ / GBN), 512, 0, stream>>>(Sgemm, w0, w1s,
                                                           ybuf);

  // 5) BN2 + LIF2 + residual -> d_out
  bn_lif_add<<<BCEL / 256, 256, 0, stream>>>(ybuf, Sgemm, bn2g, bn2b, bn2m,
                                             bn2v, (float*)d_out);
}